// Round 5
// baseline (2778.275 us; speedup 1.0000x reference)
//
#include <hip/hip_runtime.h>
#include <cstdint>
#include <cstddef>

// Replicate numpy f32 semantics: no compiler-introduced fusion anywhere.
// All intentional fusion is via explicit fmaf().
#pragma clang fp contract(off)

#define NROWS 32768          // B*C
#define NCOLS 2304           // 3*D_MODEL
#define DMODEL 768
#define QK 1536              // q+k columns
#define KCH 409
#define NBATCH 8
#define FEAT_ELEMS ((size_t)NBATCH * KCH * DMODEL)   // 2512896
#define SCALE_F 0.08838834764831845f                 // f32(128^-0.5), as numpy casts

// ---------------------------------------------------------------------------
// K1: qkv = x @ W^T + b in FLOAT32, replicating np/OpenBLAS sgemm semantics:
// one f32 accumulator per C element, k strictly ascending, fused FMA.
// Tiling only re-partitions (m,n); the per-element k-chain order is preserved.
// ---------------------------------------------------------------------------
__global__ __launch_bounds__(256) void gemm_qkv_f32(
    const float* __restrict__ x, const float* __restrict__ W,
    const float* __restrict__ bias, float* __restrict__ qkv)
{
    __shared__ float As[64][33];
    __shared__ float Bs[64][33];

    const int tid = threadIdx.x;
    const int n0 = blockIdx.x * 64;
    const int m0 = blockIdx.y * 64;
    const int tx = tid & 15;
    const int ty = tid >> 4;
    const int r  = tid >> 3;
    const int kk = (tid & 7) << 2;

    const float* xp0 = x + (size_t)(m0 + r) * DMODEL + kk;
    const float* xp1 = x + (size_t)(m0 + r + 32) * DMODEL + kk;
    const float* wp0 = W + (size_t)(n0 + r) * DMODEL + kk;
    const float* wp1 = W + (size_t)(n0 + r + 32) * DMODEL + kk;

    float acc[4][4] = {};

    for (int k0 = 0; k0 < DMODEL; k0 += 32) {
        const float4 a0 = *(const float4*)(xp0 + k0);
        const float4 a1 = *(const float4*)(xp1 + k0);
        const float4 b0 = *(const float4*)(wp0 + k0);
        const float4 b1 = *(const float4*)(wp1 + k0);
        __syncthreads();
        As[r][kk + 0] = a0.x; As[r][kk + 1] = a0.y;
        As[r][kk + 2] = a0.z; As[r][kk + 3] = a0.w;
        As[r + 32][kk + 0] = a1.x; As[r + 32][kk + 1] = a1.y;
        As[r + 32][kk + 2] = a1.z; As[r + 32][kk + 3] = a1.w;
        Bs[r][kk + 0] = b0.x; Bs[r][kk + 1] = b0.y;
        Bs[r][kk + 2] = b0.z; Bs[r][kk + 3] = b0.w;
        Bs[r + 32][kk + 0] = b1.x; Bs[r + 32][kk + 1] = b1.y;
        Bs[r + 32][kk + 2] = b1.z; Bs[r + 32][kk + 3] = b1.w;
        __syncthreads();

        #pragma unroll 4
        for (int k = 0; k < 32; ++k) {        // k ascending: 1 fmaf chain/element
            float a[4], bb[4];
            #pragma unroll
            for (int i = 0; i < 4; ++i) a[i] = As[4 * ty + i][k];
            #pragma unroll
            for (int j = 0; j < 4; ++j) bb[j] = Bs[4 * tx + j][k];
            #pragma unroll
            for (int i = 0; i < 4; ++i)
                #pragma unroll
                for (int j = 0; j < 4; ++j)
                    acc[i][j] = fmaf(a[i], bb[j], acc[i][j]);
        }
    }

    const int col0 = n0 + 4 * tx;
    #pragma unroll
    for (int i = 0; i < 4; ++i) {
        const int row = m0 + 4 * ty + i;
        float4 o;
        o.x = acc[i][0] + bias[col0 + 0];   // np: separate f32 add (b==0)
        o.y = acc[i][1] + bias[col0 + 1];
        o.z = acc[i][2] + bias[col0 + 2];
        o.w = acc[i][3] + bias[col0 + 3];
        *(float4*)(&qkv[(size_t)row * NCOLS + col0]) = o;
    }
}

// ---------------------------------------------------------------------------
// K2: per row — f32 scores (non-fused mul+add, * SCALE_F) -> per-head argmax
// (tie -> lowest g); channel norm replicating np.linalg.norm(out_f32):
// f32 squares in feature order f=d*6+h, numpy pairwise tree
// 768 -> 2x384 -> 4x192 -> 8x96, 96-leaf = 8-accumulator unrolled loop,
// combine ((r0+r1)+(r2+r3))+((r4+r5)+(r6+r7)); sqrtf. 1 wave per row.
// ---------------------------------------------------------------------------
__global__ __launch_bounds__(256) void select_and_norm(
    const float* __restrict__ qkv, float* __restrict__ norms,
    uint64_t* __restrict__ gstar)
{
    __shared__ float rowbuf[4][NCOLS];
    __shared__ float sc[4][36];
    __shared__ int   gs_s[4][6];
    __shared__ float sblk[4][8];

    const int tid  = threadIdx.x;
    const int wave = tid >> 6;
    const int lane = tid & 63;
    const int n = blockIdx.x * 4 + wave;

    {
        const float4* src = (const float4*)(qkv + (size_t)n * NCOLS);
        float4* dst = (float4*)(&rowbuf[wave][0]);
        #pragma unroll
        for (int i = 0; i < 9; ++i) dst[lane + 64 * i] = src[lane + 64 * i];
    }
    __syncthreads();

    if (lane < 36) {
        const int h = lane / 6, g = lane % 6;
        const float* qh = &rowbuf[wave][h * 128];
        const float* kh = &rowbuf[wave][768 + g * 128];
        float s = 0.0f;
        for (int d = 0; d < 128; ++d)
            s = s + qh[d] * kh[d];        // np einsum: mul then add, d ascending
        sc[wave][lane] = s * SCALE_F;
    }
    __syncthreads();

    if (lane < 6) {
        float best = sc[wave][lane * 6];
        int bg = 0;
        #pragma unroll
        for (int g = 1; g < 6; ++g) {
            const float v = sc[wave][lane * 6 + g];
            if (v > best) { best = v; bg = g; }   // strict >: lowest g on tie
        }
        gs_s[wave][lane] = bg;
    }
    __syncthreads();

    if (lane < 8) {   // lane j: numpy pairwise 96-leaf over f in [96j, 96j+96)
        const float* vr = &rowbuf[wave][QK];
        int gtab[6];
        #pragma unroll
        for (int h = 0; h < 6; ++h) gtab[h] = gs_s[wave][h];

        float r8[8];
        #pragma unroll
        for (int jj = 0; jj < 8; ++jj) {
            const int f = 96 * lane + jj;
            const float v = vr[gtab[f % 6] * 128 + f / 6];
            r8[jj] = v * v;                       // rounded square (np temp)
        }
        for (int i = 8; i < 96; i += 8) {
            #pragma unroll
            for (int jj = 0; jj < 8; ++jj) {
                const int f = 96 * lane + i + jj;
                const float v = vr[gtab[f % 6] * 128 + f / 6];
                r8[jj] = r8[jj] + v * v;
            }
        }
        sblk[wave][lane] = ((r8[0] + r8[1]) + (r8[2] + r8[3]))
                         + ((r8[4] + r8[5]) + (r8[6] + r8[7]));
    }
    __syncthreads();

    if (lane == 0) {
        const float* s = sblk[wave];
        float n2 = ((s[0] + s[1]) + (s[2] + s[3]))
                 + ((s[4] + s[5]) + (s[6] + s[7]));   // 768->384->192->96 tree
        norms[n] = sqrtf(n2);                         // IEEE sqrt = np
        uint64_t pk = 0;
        #pragma unroll
        for (int h = 0; h < 6; ++h)
            pk |= (uint64_t)gs_s[wave][h] << (8 * h);
        gstar[n] = pk;
    }
}

// ---------------------------------------------------------------------------
// K3: per batch — top-409 channels by f32 norm, descending, tie -> lower idx.
// ---------------------------------------------------------------------------
__global__ __launch_bounds__(256) void topk_channels(
    const float* __restrict__ norms, int* __restrict__ chidx,
    float* __restrict__ out)
{
    __shared__ float vals[4096];
    __shared__ float rv[256];
    __shared__ int   ri[256];
    const int b = blockIdx.x, t = threadIdx.x;

    for (int i = t; i < 4096; i += 256)
        vals[i] = norms[(size_t)b * 4096 + i];
    __syncthreads();

    for (int j = 0; j < KCH; ++j) {
        float best = -1.0f;                  // norms >= 0
        int bi = 0;
        #pragma unroll
        for (int u = 0; u < 16; ++u) {
            const int i = t + 256 * u;       // ascending: strict > keeps lowest
            const float v = vals[i];
            if (v > best) { best = v; bi = i; }
        }
        rv[t] = best; ri[t] = bi;
        __syncthreads();
        for (int s2 = 128; s2 > 0; s2 >>= 1) {
            if (t < s2) {
                const float ov = rv[t + s2]; const int oi = ri[t + s2];
                if (ov > rv[t] || (ov == rv[t] && oi < ri[t])) { rv[t] = ov; ri[t] = oi; }
            }
            __syncthreads();
        }
        if (t == 0) {
            const int w = ri[0];
            chidx[b * KCH + j] = w;
            out[FEAT_ELEMS + (size_t)b * KCH + j] = (float)w;
            vals[w] = -1.0f;
        }
        __syncthreads();
    }
    if (b == 0 && t == 0)
        out[FEAT_ELEMS + (size_t)NBATCH * KCH] = (float)KCH;   // k_channels
}

// ---------------------------------------------------------------------------
// K4: sparse_feat[b,j,f] = v[n, g*(n, f%6), f/6], n = b*4096 + ch_idx[b,j]
// (f = d*6 + h interleave from the reference's swapaxes+reshape)
// ---------------------------------------------------------------------------
__global__ __launch_bounds__(256) void gather_sparse(
    const float* __restrict__ qkv, const uint64_t* __restrict__ gstar,
    const int* __restrict__ chidx, float* __restrict__ out)
{
    const int bj = blockIdx.x;
    const int b = bj / KCH;
    const int ch = chidx[bj];
    const int n = b * 4096 + ch;
    const uint64_t pk = gstar[n];
    for (int f = threadIdx.x; f < DMODEL; f += 256) {
        const int h = f % 6;
        const int d = f / 6;
        const int g = (int)((pk >> (8 * h)) & 7u);
        out[(size_t)bj * DMODEL + f] = qkv[(size_t)n * NCOLS + QK + g * 128 + d];
    }
}

// ---------------------------------------------------------------------------
extern "C" void kernel_launch(void* const* d_in, const int* in_sizes, int n_in,
                              void* d_out, int out_size, void* d_ws, size_t ws_size,
                              hipStream_t stream)
{
    const float* x    = (const float*)d_in[0];
    const float* W    = (const float*)d_in[1];
    const float* bias = (const float*)d_in[2];
    float* out = (float*)d_out;
    char*  ws  = (char*)d_ws;

    const size_t qkvBytes   = (size_t)NROWS * NCOLS * sizeof(float);   // ~302 MB
    const size_t normsBytes = (size_t)NROWS * sizeof(float);
    const size_t gstarBytes = (size_t)NROWS * sizeof(uint64_t);
    const size_t chidxBytes = (size_t)NBATCH * KCH * sizeof(int);
    const size_t baseBytes  = qkvBytes + normsBytes + gstarBytes + chidxBytes;
    if (ws_size < baseBytes) return;   // fail visibly rather than fault

    float*    qkv   = (float*)ws;
    float*    norms = (float*)(ws + qkvBytes);
    uint64_t* gstar = (uint64_t*)(ws + qkvBytes + normsBytes);
    int*      chidx = (int*)(ws + qkvBytes + normsBytes + gstarBytes);

    gemm_qkv_f32<<<dim3(NCOLS / 64, NROWS / 64), 256, 0, stream>>>(x, W, bias, qkv);
    select_and_norm<<<NROWS / 4, 256, 0, stream>>>(qkv, norms, gstar);
    topk_channels<<<NBATCH, 256, 0, stream>>>(norms, chidx, out);
    gather_sparse<<<NBATCH * KCH, 256, 0, stream>>>(qkv, gstar, chidx, out);
}

// Round 6
// 1996.217 us; speedup vs baseline: 1.3918x; 1.3918x over previous
//
#include <hip/hip_runtime.h>
#include <cstdint>
#include <cstddef>

// Replicate numpy f32 semantics: no compiler-introduced fusion anywhere.
// All intentional fusion is via explicit fmaf().
#pragma clang fp contract(off)

#define NROWS 32768          // B*C
#define NCOLS 2304           // 3*D_MODEL
#define DMODEL 768
#define QK 1536              // q+k columns
#define KCH 409
#define NBATCH 8
#define FEAT_ELEMS ((size_t)NBATCH * KCH * DMODEL)   // 2512896
#define SCALE_F 0.08838834764831845f                 // f32(128^-0.5)

#define BM 128
#define BN 128
#define BK 32
#define RS 140   // LDS row stride in floats; max swizzled index 139

// chunk c (8 floats) -> float offset within an LDS row; spreads the 16
// 32B-chunks so any 16-lane b128 read is <=2-way bank aliased (free).
__device__ __forceinline__ int chunk_off(int c) { return 8 * c + 4 * (c >> 2); }

// ---------------------------------------------------------------------------
// K1: qkv = x @ W^T + b, f32, bit-exact numpy/OpenBLAS semantics:
// ONE accumulator per C element, k strictly ascending, fmaf chain, then a
// separate (non-fused) bias add. Tiling only re-partitions (m,n) work.
// 128x128 tile, BK=32, 256 threads, 8x8 per thread, reg-staged prefetch,
// LDS [k][m]-major with chunk swizzle for conflict-free b128 reads.
// ---------------------------------------------------------------------------
__global__ __launch_bounds__(256) void gemm_qkv_f32(
    const float* __restrict__ x, const float* __restrict__ W,
    const float* __restrict__ bias, float* __restrict__ qkv)
{
    __shared__ float As[BK * RS];
    __shared__ float Bs[BK * RS];

    const int tid = threadIdx.x;
    const int tx = tid & 15;          // output col group (8 cols)
    const int ty = tid >> 4;          // output row group (8 rows)
    const int n0 = blockIdx.x * BN;
    const int m0 = blockIdx.y * BM;

    const int sm  = tid >> 3;         // staging row 0..31 (+32 per batch)
    const int sk4 = (tid & 7) << 2;   // staging k offset 0,4,...,28

    const float* xa = x + (size_t)(m0 + sm) * DMODEL + sk4;
    const float* wb = W + (size_t)(n0 + sm) * DMODEL + sk4;

    const int aoff = chunk_off(ty);
    const int boff = chunk_off(tx);
    const int wsub = sm & 7;          // within-chunk index for staging writes
    const int wchk = sm >> 3;         // chunk base for staging writes

    float4 pa[4], pb[4];
    #pragma unroll
    for (int i = 0; i < 4; ++i) {
        pa[i] = *(const float4*)(xa + (size_t)(32 * i) * DMODEL);
        pb[i] = *(const float4*)(wb + (size_t)(32 * i) * DMODEL);
    }

    float acc[8][8] = {};

    for (int kt = 0; kt < DMODEL / BK; ++kt) {
        __syncthreads();   // previous iteration's LDS reads complete
        #pragma unroll
        for (int i = 0; i < 4; ++i) {
            const int co = chunk_off(wchk + 4 * i) + wsub;
            As[(sk4 + 0) * RS + co] = pa[i].x;
            As[(sk4 + 1) * RS + co] = pa[i].y;
            As[(sk4 + 2) * RS + co] = pa[i].z;
            As[(sk4 + 3) * RS + co] = pa[i].w;
            Bs[(sk4 + 0) * RS + co] = pb[i].x;
            Bs[(sk4 + 1) * RS + co] = pb[i].y;
            Bs[(sk4 + 2) * RS + co] = pb[i].z;
            Bs[(sk4 + 3) * RS + co] = pb[i].w;
        }
        __syncthreads();

        if (kt + 1 < DMODEL / BK) {   // prefetch next K-tile; overlaps compute
            const int ko = (kt + 1) * BK;
            #pragma unroll
            for (int i = 0; i < 4; ++i) {
                pa[i] = *(const float4*)(xa + (size_t)(32 * i) * DMODEL + ko);
                pb[i] = *(const float4*)(wb + (size_t)(32 * i) * DMODEL + ko);
            }
        }

        #pragma unroll 8
        for (int k = 0; k < BK; ++k) {   // k ascending: one fmaf chain/element
            const float* ar = &As[k * RS + aoff];
            const float* br = &Bs[k * RS + boff];
            const float4 a0 = *(const float4*)(ar);
            const float4 a1 = *(const float4*)(ar + 4);
            const float4 b0 = *(const float4*)(br);
            const float4 b1 = *(const float4*)(br + 4);
            const float a[8] = {a0.x, a0.y, a0.z, a0.w, a1.x, a1.y, a1.z, a1.w};
            const float b[8] = {b0.x, b0.y, b0.z, b0.w, b1.x, b1.y, b1.z, b1.w};
            #pragma unroll
            for (int i = 0; i < 8; ++i)
                #pragma unroll
                for (int j = 0; j < 8; ++j)
                    acc[i][j] = fmaf(a[i], b[j], acc[i][j]);
        }
    }

    const int col = n0 + 8 * tx;
    float bcol[8];
    #pragma unroll
    for (int j = 0; j < 8; ++j) bcol[j] = bias[col + j];

    #pragma unroll
    for (int i = 0; i < 8; ++i) {
        const int row = m0 + 8 * ty + i;
        float4 o0, o1;
        o0.x = acc[i][0] + bcol[0];   // np: separate f32 add (non-fused)
        o0.y = acc[i][1] + bcol[1];
        o0.z = acc[i][2] + bcol[2];
        o0.w = acc[i][3] + bcol[3];
        o1.x = acc[i][4] + bcol[4];
        o1.y = acc[i][5] + bcol[5];
        o1.z = acc[i][6] + bcol[6];
        o1.w = acc[i][7] + bcol[7];
        *(float4*)(&qkv[(size_t)row * NCOLS + col])     = o0;
        *(float4*)(&qkv[(size_t)row * NCOLS + col + 4]) = o1;
    }
}

// ---------------------------------------------------------------------------
// K2: per row — f32 scores (non-fused mul+add, * SCALE_F) -> per-head argmax
// (tie -> lowest g); channel norm replicating np.linalg.norm(out_f32):
// f32 squares in feature order f=d*6+h, numpy pairwise tree
// 768 -> 2x384 -> 4x192 -> 8x96, 96-leaf = 8-accumulator unrolled loop,
// combine ((r0+r1)+(r2+r3))+((r4+r5)+(r6+r7)); sqrtf. 1 wave per row.
// ---------------------------------------------------------------------------
__global__ __launch_bounds__(256) void select_and_norm(
    const float* __restrict__ qkv, float* __restrict__ norms,
    uint64_t* __restrict__ gstar)
{
    __shared__ float rowbuf[4][NCOLS];
    __shared__ float sc[4][36];
    __shared__ int   gs_s[4][6];
    __shared__ float sblk[4][8];

    const int tid  = threadIdx.x;
    const int wave = tid >> 6;
    const int lane = tid & 63;
    const int n = blockIdx.x * 4 + wave;

    {
        const float4* src = (const float4*)(qkv + (size_t)n * NCOLS);
        float4* dst = (float4*)(&rowbuf[wave][0]);
        #pragma unroll
        for (int i = 0; i < 9; ++i) dst[lane + 64 * i] = src[lane + 64 * i];
    }
    __syncthreads();

    if (lane < 36) {
        const int h = lane / 6, g = lane % 6;
        const float* qh = &rowbuf[wave][h * 128];
        const float* kh = &rowbuf[wave][768 + g * 128];
        float s = 0.0f;
        for (int d = 0; d < 128; ++d)
            s = s + qh[d] * kh[d];        // np einsum: mul then add, d ascending
        sc[wave][lane] = s * SCALE_F;
    }
    __syncthreads();

    if (lane < 6) {
        float best = sc[wave][lane * 6];
        int bg = 0;
        #pragma unroll
        for (int g = 1; g < 6; ++g) {
            const float v = sc[wave][lane * 6 + g];
            if (v > best) { best = v; bg = g; }   // strict >: lowest g on tie
        }
        gs_s[wave][lane] = bg;
    }
    __syncthreads();

    if (lane < 8) {   // lane j: numpy pairwise 96-leaf over f in [96j, 96j+96)
        const float* vr = &rowbuf[wave][QK];
        int gtab[6];
        #pragma unroll
        for (int h = 0; h < 6; ++h) gtab[h] = gs_s[wave][h];

        float r8[8];
        #pragma unroll
        for (int jj = 0; jj < 8; ++jj) {
            const int f = 96 * lane + jj;
            const float v = vr[gtab[f % 6] * 128 + f / 6];
            r8[jj] = v * v;                       // rounded square (np temp)
        }
        for (int i = 8; i < 96; i += 8) {
            #pragma unroll
            for (int jj = 0; jj < 8; ++jj) {
                const int f = 96 * lane + i + jj;
                const float v = vr[gtab[f % 6] * 128 + f / 6];
                r8[jj] = r8[jj] + v * v;
            }
        }
        sblk[wave][lane] = ((r8[0] + r8[1]) + (r8[2] + r8[3]))
                         + ((r8[4] + r8[5]) + (r8[6] + r8[7]));
    }
    __syncthreads();

    if (lane == 0) {
        const float* s = sblk[wave];
        float n2 = ((s[0] + s[1]) + (s[2] + s[3]))
                 + ((s[4] + s[5]) + (s[6] + s[7]));   // 768->384->192->96 tree
        norms[n] = sqrtf(n2);                         // IEEE sqrt = np
        uint64_t pk = 0;
        #pragma unroll
        for (int h = 0; h < 6; ++h)
            pk |= (uint64_t)gs_s[wave][h] << (8 * h);
        gstar[n] = pk;
    }
}

// ---------------------------------------------------------------------------
// K3: per batch — top-409 channels by f32 norm, descending, tie -> lower idx.
// ---------------------------------------------------------------------------
__global__ __launch_bounds__(256) void topk_channels(
    const float* __restrict__ norms, int* __restrict__ chidx,
    float* __restrict__ out)
{
    __shared__ float vals[4096];
    __shared__ float rv[256];
    __shared__ int   ri[256];
    const int b = blockIdx.x, t = threadIdx.x;

    for (int i = t; i < 4096; i += 256)
        vals[i] = norms[(size_t)b * 4096 + i];
    __syncthreads();

    for (int j = 0; j < KCH; ++j) {
        float best = -1.0f;                  // norms >= 0
        int bi = 0;
        #pragma unroll
        for (int u = 0; u < 16; ++u) {
            const int i = t + 256 * u;       // ascending: strict > keeps lowest
            const float v = vals[i];
            if (v > best) { best = v; bi = i; }
        }
        rv[t] = best; ri[t] = bi;
        __syncthreads();
        for (int s2 = 128; s2 > 0; s2 >>= 1) {
            if (t < s2) {
                const float ov = rv[t + s2]; const int oi = ri[t + s2];
                if (ov > rv[t] || (ov == rv[t] && oi < ri[t])) { rv[t] = ov; ri[t] = oi; }
            }
            __syncthreads();
        }
        if (t == 0) {
            const int w = ri[0];
            chidx[b * KCH + j] = w;
            out[FEAT_ELEMS + (size_t)b * KCH + j] = (float)w;
            vals[w] = -1.0f;
        }
        __syncthreads();
    }
    if (b == 0 && t == 0)
        out[FEAT_ELEMS + (size_t)NBATCH * KCH] = (float)KCH;   // k_channels
}

// ---------------------------------------------------------------------------
// K4: sparse_feat[b,j,f] = v[n, g*(n, f%6), f/6], n = b*4096 + ch_idx[b,j]
// (f = d*6 + h interleave from the reference's swapaxes+reshape)
// ---------------------------------------------------------------------------
__global__ __launch_bounds__(256) void gather_sparse(
    const float* __restrict__ qkv, const uint64_t* __restrict__ gstar,
    const int* __restrict__ chidx, float* __restrict__ out)
{
    const int bj = blockIdx.x;
    const int b = bj / KCH;
    const int ch = chidx[bj];
    const int n = b * 4096 + ch;
    const uint64_t pk = gstar[n];
    for (int f = threadIdx.x; f < DMODEL; f += 256) {
        const int h = f % 6;
        const int d = f / 6;
        const int g = (int)((pk >> (8 * h)) & 7u);
        out[(size_t)bj * DMODEL + f] = qkv[(size_t)n * NCOLS + QK + g * 128 + d];
    }
}

// ---------------------------------------------------------------------------
extern "C" void kernel_launch(void* const* d_in, const int* in_sizes, int n_in,
                              void* d_out, int out_size, void* d_ws, size_t ws_size,
                              hipStream_t stream)
{
    const float* x    = (const float*)d_in[0];
    const float* W    = (const float*)d_in[1];
    const float* bias = (const float*)d_in[2];
    float* out = (float*)d_out;
    char*  ws  = (char*)d_ws;

    const size_t qkvBytes   = (size_t)NROWS * NCOLS * sizeof(float);   // ~302 MB
    const size_t normsBytes = (size_t)NROWS * sizeof(float);
    const size_t gstarBytes = (size_t)NROWS * sizeof(uint64_t);
    const size_t chidxBytes = (size_t)NBATCH * KCH * sizeof(int);
    const size_t baseBytes  = qkvBytes + normsBytes + gstarBytes + chidxBytes;
    if (ws_size < baseBytes) return;   // fail visibly rather than fault

    float*    qkv   = (float*)ws;
    float*    norms = (float*)(ws + qkvBytes);
    uint64_t* gstar = (uint64_t*)(ws + qkvBytes + normsBytes);
    int*      chidx = (int*)(ws + qkvBytes + normsBytes + gstarBytes);

    gemm_qkv_f32<<<dim3(NCOLS / BN, NROWS / BM), 256, 0, stream>>>(x, W, bias, qkv);
    select_and_norm<<<NROWS / 4, 256, 0, stream>>>(qkv, norms, gstar);
    topk_channels<<<NBATCH, 256, 0, stream>>>(norms, chidx, out);
    gather_sparse<<<NBATCH * KCH, 256, 0, stream>>>(qkv, gstar, chidx, out);
}